// Round 8
// baseline (354.293 us; speedup 1.0000x reference)
//
#include <hip/hip_runtime.h>

typedef unsigned short u16;
typedef unsigned int   u32;
typedef __attribute__((ext_vector_type(8))) short short8;
typedef __attribute__((ext_vector_type(4))) float f32x4;
typedef __attribute__((ext_vector_type(4))) u16  u16x4;

#define DI __device__ __forceinline__

DI float b2f(u16 v){ return __builtin_bit_cast(float, (u32)v << 16); }
DI u16 f2b(float f){ u32 u = __builtin_bit_cast(u32, f); return (u16)((u + 0x7fffu + ((u >> 16) & 1u)) >> 16); }
DI float lrelu(float v){ return v > 0.f ? v : 0.01f * v; }

// ---------------- weight prep: one cvt kernel, one repack kernel -----------
__global__ __launch_bounds__(256)
void cvt_w_all(const float* __restrict__ w1, u16* __restrict__ d1,
               const float* __restrict__ w2, u16* __restrict__ d2,
               const float* __restrict__ w3, u16* __restrict__ d3,
               const float* __restrict__ w4, u16* __restrict__ d4)
{
  int i = blockIdx.x*256 + threadIdx.x;
  const float* s; u16* d; int li;
  if      (i < 1024)   { s = w1; d = d1; li = i; }
  else if (i < 5120)   { s = w2; d = d2; li = i - 1024; }
  else if (i < 70656)  { s = w3; d = d3; li = i - 5120; }
  else if (i < 1119232){ s = w4; d = d4; li = i - 70656; }
  else return;
  float4 v = ((const float4*)s)[li];
  u16x4 o; o[0]=f2b(v.x); o[1]=f2b(v.y); o[2]=f2b(v.z); o[3]=f2b(v.w);
  *(u16x4*)(d + (size_t)li*4) = o;
}

// conv weight repack into MFMA-fragment order:
//   wr[ ((tr*NK + kb)*64 + lane)*8 + j ] = w[row][c*3 + k]
//   row = tr*16 + (lane&15); kcol = kb*32 + (lane>>4)*8 + j; k = kcol>>lgC; c = kcol&(C-1)
DI void repack_one(const float* __restrict__ w, u16* __restrict__ wr,
                   int e, int C, int lgC)
{
  int R = 3*C;
  int NK   = R >> 5;
  int j    = e & 7;
  int lane = (e >> 3) & 63;
  int blk  = e >> 9;
  int tr   = blk / NK, kb = blk - tr*NK;
  int row  = tr*16 + (lane & 15);
  int kcol = kb*32 + (lane >> 4)*8 + j;
  int k = kcol >> lgC; int c = kcol & (C-1);
  wr[e] = f2b(w[(size_t)row*R + c*3 + k]);
}

__global__ __launch_bounds__(256)
void repack_all(const float* __restrict__ c1, u16* __restrict__ r1,
                const float* __restrict__ c2, u16* __restrict__ r2,
                const float* __restrict__ c3, u16* __restrict__ r3)
{
  int i = blockIdx.x*256 + threadIdx.x;
  if      (i < 24576)  repack_one(c1, r1, i,          64, 6);
  else if (i < 122880) repack_one(c2, r2, i - 24576, 128, 7);
  else if (i < 516096) repack_one(c3, r3, i - 122880,256, 8);
}

// ---------------- GEMM + fused BN-finalize/apply(A) + fused BN-stats(out) --
// Y[M,N] = act(A)[M,K] * W[N,K]^T ; act = APPLY ? lrelu(a*sc+sh) : id,
// where (sc,sh) are computed IN-BLOCK from partIn (prev layer's column sums).
// Emits per-block column sums partOut[bx*2+{0,1}][n] (s, s2).
template<int BM, int BN, int WROWS, int WCOLS, int RT, int CT, bool APPLY>
__global__ __launch_bounds__(WROWS*WCOLS*64)
void gemm_bn(const float* __restrict__ A, const u16* __restrict__ W,
             const float* __restrict__ partIn, const float* __restrict__ gA,
             const float* __restrict__ beA, int splitIn,
             float* __restrict__ Y, float* __restrict__ partOut,
             int M, int N, int K)
{
  constexpr int NT  = WROWS*WCOLS*64;
  constexpr int ALD = (BM*4)/NT;          // staging units of 8 elems
  constexpr int BLD = (BN*4)/NT;
  __shared__ __align__(16) u16 As[BM*32];
  __shared__ __align__(16) u16 Bs[BN*32];
  __shared__ float colS[WROWS][BN], colS2[WROWS][BN];
  __shared__ __align__(16) float ssL[APPLY ? 2048 : 4];   // K <= 1024
  const int tid  = threadIdx.x;
  const int wave = tid >> 6, lane = tid & 63;
  const int wr = wave / WCOLS, wc = wave % WCOLS;
  const int lrow = lane & 15, kg = lane >> 4;
  const int m0 = blockIdx.x * BM, n0 = blockIdx.y * BN;

  if constexpr (APPLY){
    // redundant per-block BN finalize for the previous layer (partIn is
    // L2-resident and tiny; identical summation order to bn_finalize)
    for (int n = tid; n < K; n += NT){
      float s = 0.f, s2 = 0.f;
      for (int i = 0; i < splitIn; i++){
        s  += partIn[(size_t)(i*2+0)*K + n];
        s2 += partIn[(size_t)(i*2+1)*K + n];
      }
      float inv  = 1.f / (float)M;
      float mean = s * inv;
      float var  = fmaxf(s2*inv - mean*mean, 0.f);
      float sc   = gA[n] * rsqrtf(var + 1e-5f);
      ssL[n]     = sc;
      ssL[K + n] = beA[n] - mean*sc;
    }
    __syncthreads();
  }

  f32x4 acc[RT][CT] = {};
  for (int k0 = 0; k0 < K; k0 += 32) {
    uint4 av[ALD], bv[BLD];
#pragma unroll
    for (int i = 0; i < ALD; i++){
      int x = tid + i*NT; int kc = k0 + (x&3)*8;
      const float* ap = A + (size_t)(m0 + (x>>2))*K + kc;
      float4 y0 = *(const float4*)ap, y1 = *(const float4*)(ap + 4);
      float v[8] = {y0.x,y0.y,y0.z,y0.w,y1.x,y1.y,y1.z,y1.w};
      if constexpr (APPLY){
        float4 c0 = *(const float4*)(ssL + kc),     c1 = *(const float4*)(ssL + kc + 4);
        float4 h0 = *(const float4*)(ssL + K + kc), h1 = *(const float4*)(ssL + K + kc + 4);
        v[0]=lrelu(v[0]*c0.x+h0.x); v[1]=lrelu(v[1]*c0.y+h0.y);
        v[2]=lrelu(v[2]*c0.z+h0.z); v[3]=lrelu(v[3]*c0.w+h0.w);
        v[4]=lrelu(v[4]*c1.x+h1.x); v[5]=lrelu(v[5]*c1.y+h1.y);
        v[6]=lrelu(v[6]*c1.z+h1.z); v[7]=lrelu(v[7]*c1.w+h1.w);
      }
      u32 w0 = (u32)f2b(v[0]) | ((u32)f2b(v[1])<<16);
      u32 w1 = (u32)f2b(v[2]) | ((u32)f2b(v[3])<<16);
      u32 w2 = (u32)f2b(v[4]) | ((u32)f2b(v[5])<<16);
      u32 w3 = (u32)f2b(v[6]) | ((u32)f2b(v[7])<<16);
      av[i] = (uint4){w0,w1,w2,w3};
    }
#pragma unroll
    for (int i = 0; i < BLD; i++){ int x = tid + i*NT; bv[i] = *(const uint4*)(W + (size_t)(n0 + (x>>2))*K + k0 + (x&3)*8); }
    __syncthreads();
#pragma unroll
    for (int i = 0; i < ALD; i++){ *(uint4*)(As + (tid + i*NT)*8) = av[i]; }
#pragma unroll
    for (int i = 0; i < BLD; i++){ *(uint4*)(Bs + (tid + i*NT)*8) = bv[i]; }
    __syncthreads();
    short8 af[RT], bfr[CT];
#pragma unroll
    for (int r = 0; r < RT; r++) af[r]  = *(const short8*)(As + ((wr*RT + r)*16 + lrow)*32 + kg*8);
#pragma unroll
    for (int c = 0; c < CT; c++) bfr[c] = *(const short8*)(Bs + ((wc*CT + c)*16 + lrow)*32 + kg*8);
#pragma unroll
    for (int r = 0; r < RT; r++)
#pragma unroll
      for (int c = 0; c < CT; c++)
        acc[r][c] = __builtin_amdgcn_mfma_f32_16x16x32_bf16(af[r], bfr[c], acc[r][c], 0, 0, 0);
  }
  // C/D: col=lane&15, row=(lane>>4)*4+i  [m89/m91]
#pragma unroll
  for (int r = 0; r < RT; r++)
#pragma unroll
    for (int c = 0; c < CT; c++)
#pragma unroll
      for (int i = 0; i < 4; i++){
        int m = m0 + (wr*RT + r)*16 + kg*4 + i;
        int n = n0 + (wc*CT + c)*16 + lrow;
        Y[(size_t)m*N + n] = acc[r][c][i];
      }
  // fused BN partial stats: column sums over this block's BM rows
#pragma unroll
  for (int c = 0; c < CT; c++){
    float s = 0.f, s2 = 0.f;
#pragma unroll
    for (int r = 0; r < RT; r++)
#pragma unroll
      for (int i = 0; i < 4; i++){ float v = acc[r][c][i]; s += v; s2 += v*v; }
    s  += __shfl_xor(s, 16);  s  += __shfl_xor(s, 32);
    s2 += __shfl_xor(s2, 16); s2 += __shfl_xor(s2, 32);
    if (kg == 0){ colS[wr][(wc*CT + c)*16 + lrow] = s; colS2[wr][(wc*CT + c)*16 + lrow] = s2; }
  }
  __syncthreads();
  if (tid < BN){
    float S = 0.f, S2 = 0.f;
#pragma unroll
    for (int w = 0; w < WROWS; w++){ S += colS[w][tid]; S2 += colS2[w][tid]; }
    partOut[(size_t)(blockIdx.x*2+0)*N + n0 + tid] = S;
    partOut[(size_t)(blockIdx.x*2+1)*N + n0 + tid] = S2;
  }
}

__global__ __launch_bounds__(256)
void bn_finalize(const float* __restrict__ part, const float* __restrict__ g,
                 const float* __restrict__ be, float* __restrict__ ss, int N, int M, int split)
{
  int n = blockIdx.x*256 + threadIdx.x;
  if (n >= N) return;
  float s = 0.f, s2 = 0.f;
  for (int i = 0; i < split; i++){ s += part[(size_t)(i*2+0)*N + n]; s2 += part[(size_t)(i*2+1)*N + n]; }
  float inv  = 1.f / (float)M;
  float mean = s * inv;
  float var  = fmaxf(s2*inv - mean*mean, 0.f);
  float sc   = g[n] * rsqrtf(var + 1e-5f);
  ss[n]     = sc;
  ss[N + n] = be[n] - mean*sc;
}

// ---------------- tree-conv + TreeLayerNorm + LeakyReLU --------------------
// R5-proven base: 8 waves, RT=O/128, combined regs <= 128 -> 2 blocks/CU.
// PMODE: 1 = full 2-stage pipeline (conv1/conv2, small acc);
//        2 = A-prefetch pipeline (conv3): next K-step's first A-half is
//            issued BEFORE this step's MFMAs -> its L2 latency hides under
//            them, and the counted-vmcnt issue order keeps it in flight.
// FIRST: XinF is Yb f32 (b,4096) channel-major pre-BN4 (fused apply+transpose).
// non-LAST out: (B, 64, O) bf16 node-major. LAST: (B,O,64) f32.
template<int C, int O, int WAVES, int MINW, int PMODE, bool LAST, bool FIRST>
__global__ __launch_bounds__(WAVES*64, MINW)
void conv_norm(const u16* __restrict__ Xin, const float* __restrict__ XinF,
               const float* __restrict__ ssA,
               const u16* __restrict__ Wr,
               const float* __restrict__ cb, const int* __restrict__ gidx,
               u16* __restrict__ Xout, float* __restrict__ Outf)
{
  constexpr int R    = 3*C;
  constexpr int NK   = R/32;               // 32-wide K blocks (6 / 12 / 24)
  constexpr int CSI  = C + 8;
  constexpr int RT   = O/(WAVES*16);       // weight-row tiles per wave
  constexpr int RH   = (RT >= 2) ? RT/2 : 1;
  constexpr int NT   = WAVES*64;
  constexpr int LGC  = (C==64)?6:((C==128)?7:8);
  constexpr int LG32 = LGC - 5;            // kb32 -> tap index shift
  __shared__ __align__(16) u16 xs[65*CSI];
  __shared__ int idxs[192];
  __shared__ float red[2*WAVES];
  const int b = blockIdx.x, tid = threadIdx.x;
  const int wave = tid >> 6, lane = tid & 63;
  const int lrow = lane & 15, kg = lane >> 4;

  if constexpr (FIRST){
    // Yb[b][j], j = c*64 + n ; apply BN4+lrelu, transpose into xs[n][c]
    const float* yg = XinF + (size_t)b*4096;
    int j0 = tid*8;                        // NT=512 threads x 8 = 4096
    float4 a0 = *(const float4*)(yg + j0);
    float4 a1 = *(const float4*)(yg + j0 + 4);
    float4 s0 = *(const float4*)(ssA + j0);
    float4 s1 = *(const float4*)(ssA + j0 + 4);
    float4 h0 = *(const float4*)(ssA + 4096 + j0);
    float4 h1 = *(const float4*)(ssA + 4096 + j0 + 4);
    int c = j0 >> 6, n0 = j0 & 63;
    u16* xp = xs + c;
    xp[(n0+0)*CSI] = f2b(lrelu(a0.x*s0.x + h0.x));
    xp[(n0+1)*CSI] = f2b(lrelu(a0.y*s0.y + h0.y));
    xp[(n0+2)*CSI] = f2b(lrelu(a0.z*s0.z + h0.z));
    xp[(n0+3)*CSI] = f2b(lrelu(a0.w*s0.w + h0.w));
    xp[(n0+4)*CSI] = f2b(lrelu(a1.x*s1.x + h1.x));
    xp[(n0+5)*CSI] = f2b(lrelu(a1.y*s1.y + h1.y));
    xp[(n0+6)*CSI] = f2b(lrelu(a1.z*s1.z + h1.z));
    xp[(n0+7)*CSI] = f2b(lrelu(a1.w*s1.w + h1.w));
  } else {
    const u16* xg = Xin + (size_t)b*64*C;
    for (int e = tid; e < 64*(C/8); e += NT){
      int row = e/(C/8), t = e%(C/8);
      *(uint4*)(xs + row*CSI + t*8) = *(const uint4*)(xg + row*C + t*8);
    }
  }
  for (int e = tid; e < C/8; e += NT){ uint4 z = {0,0,0,0}; *(uint4*)(xs + 64*CSI + e*8) = z; }
  if (tid < 189){ int v = gidx[b*189 + tid]; idxs[tid] = v & 63; }
  __syncthreads();

  // gathered node row per (output-node ct, tap k), separate register arrays
  // so tap selection is two cndmasks — no scratch (rule #20).
  int jr0[4], jr1[4], jr2[4];
#pragma unroll
  for (int ct = 0; ct < 4; ct++){
    int n = ct*16 + lrow;
    jr0[ct] = (n == 0) ? 64 : idxs[3*(n-1) + 0];
    jr1[ct] = (n == 0) ? 64 : idxs[3*(n-1) + 1];
    jr2[ct] = (n == 0) ? 64 : idxs[3*(n-1) + 2];
  }

  const u16* wbase = Wr + ((size_t)wave*NK << 9) + lane*8;  // coalesced frag base (r=0)

  auto loadA = [&](short8* af, int kb32){
#pragma unroll
    for (int r = 0; r < RT; r++)
      af[r] = *(const short8*)(wbase + (((size_t)(WAVES*r)*NK + kb32) << 9));
  };
  auto loadAh = [&](short8* af, int kb32, int h){       // half RT (reg-lean path)
#pragma unroll
    for (int j = 0; j < RH; j++)
      af[j] = *(const short8*)(wbase + (((size_t)(WAVES*(h*RH + j))*NK + kb32) << 9));
  };
  auto loadB = [&](short8* bfr, int kb32){
    const int k  = kb32 >> LG32;
    const int c0 = ((kb32*32) & (C-1)) + kg*8;
#pragma unroll
    for (int ct = 0; ct < 4; ct++){
      int row = (k == 0) ? jr0[ct] : ((k == 1) ? jr1[ct] : jr2[ct]);
      bfr[ct] = *(const short8*)(xs + row*CSI + c0);
    }
  };

  f32x4 acc[RT][4] = {};

  if constexpr (PMODE == 1) {
    short8 afA[RT], bfA[4], afB[RT], bfB[4];
    auto domfma = [&](short8* af, short8* bfr){
      __builtin_amdgcn_s_setprio(1);
#pragma unroll
      for (int r = 0; r < RT; r++)
#pragma unroll
        for (int ct = 0; ct < 4; ct++)
          acc[r][ct] = __builtin_amdgcn_mfma_f32_16x16x32_bf16(af[r], bfr[ct], acc[r][ct], 0, 0, 0);
      __builtin_amdgcn_s_setprio(0);
    };
    loadA(afA, 0); loadB(bfA, 0);
    for (int kb32 = 0; kb32 < NK; kb32 += 2){    // NK always even (6/12/24)
      loadA(afB, kb32+1); loadB(bfB, kb32+1);    // prefetch odd stage
      domfma(afA, bfA);
      if (kb32 + 2 < NK){ loadA(afA, kb32+2); loadB(bfA, kb32+2); }
      domfma(afB, bfB);
    }
  } else {
    // PMODE 2: A-h0 prefetched one K-step ahead (double-buffered afP0/afP1);
    // per step: loadB -> loadA_h1 -> prefetch next h0 -> MFMA(h0) -> MFMA(h1).
    // MFMA(h0) drains vmcnt only to 4 (h1+prefetch outstanding): the
    // prefetch's L2 latency hides under this step's 16 MFMAs.
    auto half_mfma = [&](short8* afh, short8* bfr, int h){
      __builtin_amdgcn_s_setprio(1);
#pragma unroll
      for (int j = 0; j < RH; j++)
#pragma unroll
        for (int ct = 0; ct < 4; ct++)
          acc[h*RH + j][ct] = __builtin_amdgcn_mfma_f32_16x16x32_bf16(afh[j], bfr[ct], acc[h*RH + j][ct], 0, 0, 0);
      __builtin_amdgcn_s_setprio(0);
    };
    short8 afP0[RH], afP1[RH];
    loadAh(afP0, 0, 0);
    for (int kb32 = 0; kb32 < NK; kb32 += 2){    // NK even
      {
        short8 bfr[4]; loadB(bfr, kb32);
        short8 af1[RH]; loadAh(af1, kb32, 1);
        loadAh(afP1, kb32+1, 0);                 // prefetch next step's h0
        half_mfma(afP0, bfr, 0);
        half_mfma(af1,  bfr, 1);
      }
      {
        short8 bfr[4]; loadB(bfr, kb32+1);
        short8 af1[RH]; loadAh(af1, kb32+1, 1);
        if (kb32 + 2 < NK) loadAh(afP0, kb32+2, 0);
        half_mfma(afP1, bfr, 0);
        half_mfma(af1,  bfr, 1);
      }
    }
  }

  // bias (skip null column 0) + per-sample stats over (O x 64)
  float s = 0.f, s2 = 0.f;
#pragma unroll
  for (int r = 0; r < RT; r++)
#pragma unroll
    for (int i = 0; i < 4; i++){
      int o = (wave + WAVES*r)*16 + kg*4 + i;
      float bias = cb[o];
#pragma unroll
      for (int ct = 0; ct < 4; ct++){
        int n = ct*16 + lrow;
        float v = acc[r][ct][i];
        if (n != 0) v += bias;
        acc[r][ct][i] = v;
        s += v; s2 += v*v;
      }
    }
#pragma unroll
  for (int off = 32; off > 0; off >>= 1){ s += __shfl_down(s, off); s2 += __shfl_down(s2, off); }
  if (lane == 0){ red[wave] = s; red[WAVES + wave] = s2; }
  __syncthreads();
  if (tid == 0){
    float S = 0.f, S2 = 0.f;
    for (int w = 0; w < WAVES; w++){ S += red[w]; S2 += red[WAVES + w]; }
    const float NV = (float)(O*64);
    float mean = S / NV;
    float var  = fmaxf(S2/NV - mean*mean, 0.f) * (NV/(NV-1.f));  // torch.std ddof=1
    float sc   = 1.f / (sqrtf(var) + 1e-5f);
    red[0] = mean; red[1] = sc;
  }
  __syncthreads();
  const float mean = red[0], sc = red[1];

  if constexpr (LAST) {
#pragma unroll
    for (int r = 0; r < RT; r++)
#pragma unroll
      for (int ct = 0; ct < 4; ct++)
#pragma unroll
        for (int i = 0; i < 4; i++){
          int o = (wave + WAVES*r)*16 + kg*4 + i;
          int n = ct*16 + lrow;
          Outf[(size_t)b*(O*64) + o*64 + n] = lrelu((acc[r][ct][i] - mean)*sc);  // f32 output
        }
  } else {
#pragma unroll
    for (int r = 0; r < RT; r++)
#pragma unroll
      for (int ct = 0; ct < 4; ct++){
        int o0 = (wave + WAVES*r)*16 + kg*4;
        int n  = ct*16 + lrow;
        u16x4 pk;
#pragma unroll
        for (int i = 0; i < 4; i++) pk[i] = f2b(lrelu((acc[r][ct][i] - mean)*sc));
        *(u16x4*)(Xout + (size_t)b*64*O + (size_t)n*O + o0) = pk;  // (B,64,O) node-major
      }
  }
}

// ---------------------------------------------------------------------------
extern "C" void kernel_launch(void* const* d_in, const int* in_sizes, int n_in,
                              void* d_out, int out_size, void* d_ws, size_t ws_size,
                              hipStream_t stream)
{
  // ALL float inputs are float32 (proven by R3's dtype-flag experiment).
  const float* trees = (const float*)d_in[0];
  const int*   gidx  = (const int*)d_in[1];
  const float* w1 = (const float*)d_in[2];
  const float* g1 = (const float*)d_in[4];  const float* be1 = (const float*)d_in[5];
  const float* w2 = (const float*)d_in[6];
  const float* g2 = (const float*)d_in[8];  const float* be2 = (const float*)d_in[9];
  const float* w3 = (const float*)d_in[10];
  const float* g3 = (const float*)d_in[12]; const float* be3 = (const float*)d_in[13];
  const float* w4 = (const float*)d_in[14];
  const float* g4 = (const float*)d_in[16]; const float* be4 = (const float*)d_in[17];
  const float* cw1 = (const float*)d_in[18]; const float* cb1 = (const float*)d_in[19];
  const float* cw2 = (const float*)d_in[20]; const float* cb2 = (const float*)d_in[21];
  const float* cw3 = (const float*)d_in[22]; const float* cb3 = (const float*)d_in[23];
  // linear biases b1..b4 cancel under training-mode BN — unused.

  // ws: repacked conv weights + BN scratch + Xc3 (must NOT alias d_out).
  char* ws = (char*)d_ws;
  size_t off = 0;
  auto alloc = [&](size_t bytes)->char*{ char* p = ws + off; off += (bytes + 255) & ~(size_t)255; return p; };
  u16*   Wr1   = (u16*)  alloc(128*192*2);
  u16*   Wr2   = (u16*)  alloc(256*384*2);
  u16*   Wr3   = (u16*)  alloc(512*768*2);
  float* partA = (float*)alloc(64*4096*4);
  float* partB = (float*)alloc(64*4096*4);
  float* ss4   = (float*)alloc(2*4096*4);
  u16*   Xc3   = (u16*)  alloc((size_t)2048*64*256*2);   // 64 MB

  // d_out is (2048,512,64) FLOAT32 = 268 MB. Host MLP-phase scratch inside it;
  // everything here is dead before the final conv overwrites all of d_out.
  u16*   ob   = (u16*)d_out;                 // u16-unit view for offsets
  float* outF = (float*)d_out;
  float* Ya   = (float*)ob;                  // u16 [0, 16,777,216)  : f32 ping
  u16*   Wb1  = ob + 19660800;               // [.., 19,664,896)
  u16*   Wb2  = ob + 19664896;               // [.., 19,681,280)
  u16*   Wb3  = ob + 19681280;               // [.., 19,943,424)
  u16*   Wb4  = ob + 19943424;               // [.., 24,137,728)
  u16*   Xc2  = ob + 33554432;               // [.., 50,331,648)
  float* Yb   = (float*)(ob + 50331648);     // [.., 67,108,864)  : f32 pong  < 134,217,728 ✓

  // weight prep (2 launches)
  cvt_w_all <<<4372, 256, 0, stream>>>(w1, Wb1, w2, Wb2, w3, Wb3, w4, Wb4);
  repack_all<<<2016, 256, 0, stream>>>(cw1, Wr1, cw2, Wr2, cw3, Wr3);

  // MLP: gemm(+stats) -> next gemm finalizes+applies BN on its A-load.
  gemm_bn<64,64,4,1,1,4,false><<<dim3(32,1),  256, 0, stream>>>(trees, Wb1, nullptr, nullptr, nullptr, 0,  Ya, partA, 2048, 64,   64);
  gemm_bn<64,64,4,1,1,4,true ><<<dim3(32,4),  256, 0, stream>>>(Ya,    Wb2, partA,   g1,      be1,     32, Yb, partB, 2048, 256,  64);
  gemm_bn<64,64,4,1,1,4,true ><<<dim3(32,16), 256, 0, stream>>>(Yb,    Wb3, partB,   g2,      be2,     32, Ya, partA, 2048, 1024, 256);
  gemm_bn<128,256,2,4,4,4,true><<<dim3(16,16),512, 0, stream>>>(Ya,    Wb4, partA,   g3,      be3,     32, Yb, partB, 2048, 4096, 1024);
  bn_finalize<<<16, 256, 0, stream>>>(partB, g4, be4, ss4, 4096, 2048, 16);

  // tree-conv stack: conv1/conv2 full 2-stage pipeline (PMODE 1);
  // conv3 A-prefetch pipeline (PMODE 2) within the 128-reg wall.
  conv_norm< 64,128,8,4,1,false,true ><<<2048, 512, 0, stream>>>(nullptr, Yb, ss4, Wr1, cb1, gidx, Xc2, nullptr);
  conv_norm<128,256,8,4,1,false,false><<<2048, 512, 0, stream>>>(Xc2, nullptr, nullptr, Wr2, cb2, gidx, Xc3, nullptr);
  conv_norm<256,512,8,4,2,true ,false><<<2048, 512, 0, stream>>>(Xc3, nullptr, nullptr, Wr3, cb3, gidx, nullptr, outF);
}

// Round 9
// 349.919 us; speedup vs baseline: 1.0125x; 1.0125x over previous
//
#include <hip/hip_runtime.h>

typedef unsigned short u16;
typedef unsigned int   u32;
typedef __attribute__((ext_vector_type(8))) short short8;
typedef __attribute__((ext_vector_type(4))) float f32x4;
typedef __attribute__((ext_vector_type(4))) u16  u16x4;

#define DI __device__ __forceinline__

DI float b2f(u16 v){ return __builtin_bit_cast(float, (u32)v << 16); }
DI u16 f2b(float f){ u32 u = __builtin_bit_cast(u32, f); return (u16)((u + 0x7fffu + ((u >> 16) & 1u)) >> 16); }
DI float lrelu(float v){ return v > 0.f ? v : 0.01f * v; }

// ---------------- weight prep: one cvt kernel, one repack kernel -----------
__global__ __launch_bounds__(256)
void cvt_w_all(const float* __restrict__ w1, u16* __restrict__ d1,
               const float* __restrict__ w2, u16* __restrict__ d2,
               const float* __restrict__ w3, u16* __restrict__ d3,
               const float* __restrict__ w4, u16* __restrict__ d4)
{
  int i = blockIdx.x*256 + threadIdx.x;
  const float* s; u16* d; int li;
  if      (i < 1024)   { s = w1; d = d1; li = i; }
  else if (i < 5120)   { s = w2; d = d2; li = i - 1024; }
  else if (i < 70656)  { s = w3; d = d3; li = i - 5120; }
  else if (i < 1119232){ s = w4; d = d4; li = i - 70656; }
  else return;
  float4 v = ((const float4*)s)[li];
  u16x4 o; o[0]=f2b(v.x); o[1]=f2b(v.y); o[2]=f2b(v.z); o[3]=f2b(v.w);
  *(u16x4*)(d + (size_t)li*4) = o;
}

// conv weight repack into MFMA-fragment order:
//   wr[ ((tr*NK + kb)*64 + lane)*8 + j ] = w[row][c*3 + k]
//   row = tr*16 + (lane&15); kcol = kb*32 + (lane>>4)*8 + j; k = kcol>>lgC; c = kcol&(C-1)
DI void repack_one(const float* __restrict__ w, u16* __restrict__ wr,
                   int e, int C, int lgC)
{
  int R = 3*C;
  int NK   = R >> 5;
  int j    = e & 7;
  int lane = (e >> 3) & 63;
  int blk  = e >> 9;
  int tr   = blk / NK, kb = blk - tr*NK;
  int row  = tr*16 + (lane & 15);
  int kcol = kb*32 + (lane >> 4)*8 + j;
  int k = kcol >> lgC; int c = kcol & (C-1);
  wr[e] = f2b(w[(size_t)row*R + c*3 + k]);
}

__global__ __launch_bounds__(256)
void repack_all(const float* __restrict__ c1, u16* __restrict__ r1,
                const float* __restrict__ c2, u16* __restrict__ r2,
                const float* __restrict__ c3, u16* __restrict__ r3)
{
  int i = blockIdx.x*256 + threadIdx.x;
  if      (i < 24576)  repack_one(c1, r1, i,          64, 6);
  else if (i < 122880) repack_one(c2, r2, i - 24576, 128, 7);
  else if (i < 516096) repack_one(c3, r3, i - 122880,256, 8);
}

// ---------------- GEMM + fused BN-finalize/apply(A) + fused BN-stats(out) --
// Y[M,N] = act(A)[M,K] * W[N,K]^T ; act = APPLY ? lrelu(a*sc+sh) : id,
// where (sc,sh) are computed IN-BLOCK from partIn (prev layer's column sums).
// Emits per-block column sums partOut[bx*2+{0,1}][n] (s, s2).
template<int BM, int BN, int WROWS, int WCOLS, int RT, int CT, bool APPLY>
__global__ __launch_bounds__(WROWS*WCOLS*64)
void gemm_bn(const float* __restrict__ A, const u16* __restrict__ W,
             const float* __restrict__ partIn, const float* __restrict__ gA,
             const float* __restrict__ beA, int splitIn,
             float* __restrict__ Y, float* __restrict__ partOut,
             int M, int N, int K)
{
  constexpr int NT  = WROWS*WCOLS*64;
  constexpr int ALD = (BM*4)/NT;          // staging units of 8 elems
  constexpr int BLD = (BN*4)/NT;
  __shared__ __align__(16) u16 As[BM*32];
  __shared__ __align__(16) u16 Bs[BN*32];
  __shared__ float colS[WROWS][BN], colS2[WROWS][BN];
  __shared__ __align__(16) float ssL[APPLY ? 2048 : 4];   // K <= 1024
  const int tid  = threadIdx.x;
  const int wave = tid >> 6, lane = tid & 63;
  const int wr = wave / WCOLS, wc = wave % WCOLS;
  const int lrow = lane & 15, kg = lane >> 4;
  const int m0 = blockIdx.x * BM, n0 = blockIdx.y * BN;

  if constexpr (APPLY){
    // redundant per-block BN finalize for the previous layer (partIn is
    // L2-resident and tiny; identical summation order to bn_finalize)
    for (int n = tid; n < K; n += NT){
      float s = 0.f, s2 = 0.f;
      for (int i = 0; i < splitIn; i++){
        s  += partIn[(size_t)(i*2+0)*K + n];
        s2 += partIn[(size_t)(i*2+1)*K + n];
      }
      float inv  = 1.f / (float)M;
      float mean = s * inv;
      float var  = fmaxf(s2*inv - mean*mean, 0.f);
      float sc   = gA[n] * rsqrtf(var + 1e-5f);
      ssL[n]     = sc;
      ssL[K + n] = beA[n] - mean*sc;
    }
    __syncthreads();
  }

  f32x4 acc[RT][CT] = {};
  for (int k0 = 0; k0 < K; k0 += 32) {
    uint4 av[ALD], bv[BLD];
#pragma unroll
    for (int i = 0; i < ALD; i++){
      int x = tid + i*NT; int kc = k0 + (x&3)*8;
      const float* ap = A + (size_t)(m0 + (x>>2))*K + kc;
      float4 y0 = *(const float4*)ap, y1 = *(const float4*)(ap + 4);
      float v[8] = {y0.x,y0.y,y0.z,y0.w,y1.x,y1.y,y1.z,y1.w};
      if constexpr (APPLY){
        float4 c0 = *(const float4*)(ssL + kc),     c1 = *(const float4*)(ssL + kc + 4);
        float4 h0 = *(const float4*)(ssL + K + kc), h1 = *(const float4*)(ssL + K + kc + 4);
        v[0]=lrelu(v[0]*c0.x+h0.x); v[1]=lrelu(v[1]*c0.y+h0.y);
        v[2]=lrelu(v[2]*c0.z+h0.z); v[3]=lrelu(v[3]*c0.w+h0.w);
        v[4]=lrelu(v[4]*c1.x+h1.x); v[5]=lrelu(v[5]*c1.y+h1.y);
        v[6]=lrelu(v[6]*c1.z+h1.z); v[7]=lrelu(v[7]*c1.w+h1.w);
      }
      u32 w0 = (u32)f2b(v[0]) | ((u32)f2b(v[1])<<16);
      u32 w1 = (u32)f2b(v[2]) | ((u32)f2b(v[3])<<16);
      u32 w2 = (u32)f2b(v[4]) | ((u32)f2b(v[5])<<16);
      u32 w3 = (u32)f2b(v[6]) | ((u32)f2b(v[7])<<16);
      av[i] = (uint4){w0,w1,w2,w3};
    }
#pragma unroll
    for (int i = 0; i < BLD; i++){ int x = tid + i*NT; bv[i] = *(const uint4*)(W + (size_t)(n0 + (x>>2))*K + k0 + (x&3)*8); }
    __syncthreads();
#pragma unroll
    for (int i = 0; i < ALD; i++){ *(uint4*)(As + (tid + i*NT)*8) = av[i]; }
#pragma unroll
    for (int i = 0; i < BLD; i++){ *(uint4*)(Bs + (tid + i*NT)*8) = bv[i]; }
    __syncthreads();
    short8 af[RT], bfr[CT];
#pragma unroll
    for (int r = 0; r < RT; r++) af[r]  = *(const short8*)(As + ((wr*RT + r)*16 + lrow)*32 + kg*8);
#pragma unroll
    for (int c = 0; c < CT; c++) bfr[c] = *(const short8*)(Bs + ((wc*CT + c)*16 + lrow)*32 + kg*8);
#pragma unroll
    for (int r = 0; r < RT; r++)
#pragma unroll
      for (int c = 0; c < CT; c++)
        acc[r][c] = __builtin_amdgcn_mfma_f32_16x16x32_bf16(af[r], bfr[c], acc[r][c], 0, 0, 0);
  }
  // C/D: col=lane&15, row=(lane>>4)*4+i  [m89/m91]
#pragma unroll
  for (int r = 0; r < RT; r++)
#pragma unroll
    for (int c = 0; c < CT; c++)
#pragma unroll
      for (int i = 0; i < 4; i++){
        int m = m0 + (wr*RT + r)*16 + kg*4 + i;
        int n = n0 + (wc*CT + c)*16 + lrow;
        Y[(size_t)m*N + n] = acc[r][c][i];
      }
  // fused BN partial stats: column sums over this block's BM rows
#pragma unroll
  for (int c = 0; c < CT; c++){
    float s = 0.f, s2 = 0.f;
#pragma unroll
    for (int r = 0; r < RT; r++)
#pragma unroll
      for (int i = 0; i < 4; i++){ float v = acc[r][c][i]; s += v; s2 += v*v; }
    s  += __shfl_xor(s, 16);  s  += __shfl_xor(s, 32);
    s2 += __shfl_xor(s2, 16); s2 += __shfl_xor(s2, 32);
    if (kg == 0){ colS[wr][(wc*CT + c)*16 + lrow] = s; colS2[wr][(wc*CT + c)*16 + lrow] = s2; }
  }
  __syncthreads();
  if (tid < BN){
    float S = 0.f, S2 = 0.f;
#pragma unroll
    for (int w = 0; w < WROWS; w++){ S += colS[w][tid]; S2 += colS2[w][tid]; }
    partOut[(size_t)(blockIdx.x*2+0)*N + n0 + tid] = S;
    partOut[(size_t)(blockIdx.x*2+1)*N + n0 + tid] = S2;
  }
}

__global__ __launch_bounds__(256)
void bn_finalize(const float* __restrict__ part, const float* __restrict__ g,
                 const float* __restrict__ be, float* __restrict__ ss, int N, int M, int split)
{
  int n = blockIdx.x*256 + threadIdx.x;
  if (n >= N) return;
  float s = 0.f, s2 = 0.f;
  for (int i = 0; i < split; i++){ s += part[(size_t)(i*2+0)*N + n]; s2 += part[(size_t)(i*2+1)*N + n]; }
  float inv  = 1.f / (float)M;
  float mean = s * inv;
  float var  = fmaxf(s2*inv - mean*mean, 0.f);
  float sc   = g[n] * rsqrtf(var + 1e-5f);
  ss[n]     = sc;
  ss[N + n] = be[n] - mean*sc;
}

// ---------------- tree-conv + TreeLayerNorm + LeakyReLU --------------------
// R5-proven structure (best measured, twice): 8 waves, RT=O/128, combined
// regs <= 128 -> 2 blocks/CU (4 waves/SIMD). PIPE=true: 2-stage register
// pipeline (conv1/conv2, small acc). PIPE=false: single-stage with A loaded
// in two halves to cap peak registers (conv3; R2/R8 proved deeper
// ILP/prefetch at this occupancy is neutral-to-negative).
// FIRST: XinF is Yb f32 (b,4096) channel-major pre-BN4 (fused apply+transpose).
// non-LAST out: (B, 64, O) bf16 node-major. LAST: (B,O,64) f32.
template<int C, int O, int WAVES, int MINW, bool PIPE, bool LAST, bool FIRST>
__global__ __launch_bounds__(WAVES*64, MINW)
void conv_norm(const u16* __restrict__ Xin, const float* __restrict__ XinF,
               const float* __restrict__ ssA,
               const u16* __restrict__ Wr,
               const float* __restrict__ cb, const int* __restrict__ gidx,
               u16* __restrict__ Xout, float* __restrict__ Outf)
{
  constexpr int R    = 3*C;
  constexpr int NK   = R/32;               // 32-wide K blocks (6 / 12 / 24)
  constexpr int CSI  = C + 8;
  constexpr int RT   = O/(WAVES*16);       // weight-row tiles per wave
  constexpr int RH   = (RT >= 2) ? RT/2 : 1;
  constexpr int NT   = WAVES*64;
  constexpr int LGC  = (C==64)?6:((C==128)?7:8);
  constexpr int LG32 = LGC - 5;            // kb32 -> tap index shift
  __shared__ __align__(16) u16 xs[65*CSI];
  __shared__ int idxs[192];
  __shared__ float red[2*WAVES];
  const int b = blockIdx.x, tid = threadIdx.x;
  const int wave = tid >> 6, lane = tid & 63;
  const int lrow = lane & 15, kg = lane >> 4;

  if constexpr (FIRST){
    // Yb[b][j], j = c*64 + n ; apply BN4+lrelu, transpose into xs[n][c]
    const float* yg = XinF + (size_t)b*4096;
    int j0 = tid*8;                        // NT=512 threads x 8 = 4096
    float4 a0 = *(const float4*)(yg + j0);
    float4 a1 = *(const float4*)(yg + j0 + 4);
    float4 s0 = *(const float4*)(ssA + j0);
    float4 s1 = *(const float4*)(ssA + j0 + 4);
    float4 h0 = *(const float4*)(ssA + 4096 + j0);
    float4 h1 = *(const float4*)(ssA + 4096 + j0 + 4);
    int c = j0 >> 6, n0 = j0 & 63;
    u16* xp = xs + c;
    xp[(n0+0)*CSI] = f2b(lrelu(a0.x*s0.x + h0.x));
    xp[(n0+1)*CSI] = f2b(lrelu(a0.y*s0.y + h0.y));
    xp[(n0+2)*CSI] = f2b(lrelu(a0.z*s0.z + h0.z));
    xp[(n0+3)*CSI] = f2b(lrelu(a0.w*s0.w + h0.w));
    xp[(n0+4)*CSI] = f2b(lrelu(a1.x*s1.x + h1.x));
    xp[(n0+5)*CSI] = f2b(lrelu(a1.y*s1.y + h1.y));
    xp[(n0+6)*CSI] = f2b(lrelu(a1.z*s1.z + h1.z));
    xp[(n0+7)*CSI] = f2b(lrelu(a1.w*s1.w + h1.w));
  } else {
    const u16* xg = Xin + (size_t)b*64*C;
    for (int e = tid; e < 64*(C/8); e += NT){
      int row = e/(C/8), t = e%(C/8);
      *(uint4*)(xs + row*CSI + t*8) = *(const uint4*)(xg + row*C + t*8);
    }
  }
  for (int e = tid; e < C/8; e += NT){ uint4 z = {0,0,0,0}; *(uint4*)(xs + 64*CSI + e*8) = z; }
  if (tid < 189){ int v = gidx[b*189 + tid]; idxs[tid] = v & 63; }
  __syncthreads();

  // gathered node row per (output-node ct, tap k), separate register arrays
  // so tap selection is two cndmasks — no scratch (rule #20).
  int jr0[4], jr1[4], jr2[4];
#pragma unroll
  for (int ct = 0; ct < 4; ct++){
    int n = ct*16 + lrow;
    jr0[ct] = (n == 0) ? 64 : idxs[3*(n-1) + 0];
    jr1[ct] = (n == 0) ? 64 : idxs[3*(n-1) + 1];
    jr2[ct] = (n == 0) ? 64 : idxs[3*(n-1) + 2];
  }

  const u16* wbase = Wr + ((size_t)wave*NK << 9) + lane*8;  // coalesced frag base (r=0)

  auto loadA = [&](short8* af, int kb32){
#pragma unroll
    for (int r = 0; r < RT; r++)
      af[r] = *(const short8*)(wbase + (((size_t)(WAVES*r)*NK + kb32) << 9));
  };
  auto loadAh = [&](short8* af, int kb32, int h){       // half RT (reg-lean path)
#pragma unroll
    for (int j = 0; j < RH; j++)
      af[j] = *(const short8*)(wbase + (((size_t)(WAVES*(h*RH + j))*NK + kb32) << 9));
  };
  auto loadB = [&](short8* bfr, int kb32){
    const int k  = kb32 >> LG32;
    const int c0 = ((kb32*32) & (C-1)) + kg*8;
#pragma unroll
    for (int ct = 0; ct < 4; ct++){
      int row = (k == 0) ? jr0[ct] : ((k == 1) ? jr1[ct] : jr2[ct]);
      bfr[ct] = *(const short8*)(xs + row*CSI + c0);
    }
  };

  f32x4 acc[RT][4] = {};

  if constexpr (PIPE) {
    short8 afA[RT], bfA[4], afB[RT], bfB[4];
    auto domfma = [&](short8* af, short8* bfr){
      __builtin_amdgcn_s_setprio(1);
#pragma unroll
      for (int r = 0; r < RT; r++)
#pragma unroll
        for (int ct = 0; ct < 4; ct++)
          acc[r][ct] = __builtin_amdgcn_mfma_f32_16x16x32_bf16(af[r], bfr[ct], acc[r][ct], 0, 0, 0);
      __builtin_amdgcn_s_setprio(0);
    };
    loadA(afA, 0); loadB(bfA, 0);
    for (int kb32 = 0; kb32 < NK; kb32 += 2){    // NK always even (6/12/24)
      loadA(afB, kb32+1); loadB(bfB, kb32+1);    // prefetch odd stage
      domfma(afA, bfA);
      if (kb32 + 2 < NK){ loadA(afA, kb32+2); loadB(bfA, kb32+2); }
      domfma(afB, bfB);
    }
  } else {
    // single-stage, A loaded in two halves to cap peak registers (R2 cliff)
    for (int kb32 = 0; kb32 < NK; kb32++){
      short8 bfr[4];
      loadB(bfr, kb32);
      short8 af0[RH];
      loadAh(af0, kb32, 0);
      __builtin_amdgcn_s_setprio(1);
#pragma unroll
      for (int j = 0; j < RH; j++)
#pragma unroll
        for (int ct = 0; ct < 4; ct++)
          acc[j][ct] = __builtin_amdgcn_mfma_f32_16x16x32_bf16(af0[j], bfr[ct], acc[j][ct], 0, 0, 0);
      __builtin_amdgcn_s_setprio(0);
      short8 af1[RH];
      loadAh(af1, kb32, 1);
      __builtin_amdgcn_s_setprio(1);
#pragma unroll
      for (int j = 0; j < RH; j++)
#pragma unroll
        for (int ct = 0; ct < 4; ct++)
          acc[RH + j][ct] = __builtin_amdgcn_mfma_f32_16x16x32_bf16(af1[j], bfr[ct], acc[RH + j][ct], 0, 0, 0);
      __builtin_amdgcn_s_setprio(0);
    }
  }

  // bias (skip null column 0) + per-sample stats over (O x 64)
  float s = 0.f, s2 = 0.f;
#pragma unroll
  for (int r = 0; r < RT; r++)
#pragma unroll
    for (int i = 0; i < 4; i++){
      int o = (wave + WAVES*r)*16 + kg*4 + i;
      float bias = cb[o];
#pragma unroll
      for (int ct = 0; ct < 4; ct++){
        int n = ct*16 + lrow;
        float v = acc[r][ct][i];
        if (n != 0) v += bias;
        acc[r][ct][i] = v;
        s += v; s2 += v*v;
      }
    }
#pragma unroll
  for (int off = 32; off > 0; off >>= 1){ s += __shfl_down(s, off); s2 += __shfl_down(s2, off); }
  if (lane == 0){ red[wave] = s; red[WAVES + wave] = s2; }
  __syncthreads();
  if (tid == 0){
    float S = 0.f, S2 = 0.f;
    for (int w = 0; w < WAVES; w++){ S += red[w]; S2 += red[WAVES + w]; }
    const float NV = (float)(O*64);
    float mean = S / NV;
    float var  = fmaxf(S2/NV - mean*mean, 0.f) * (NV/(NV-1.f));  // torch.std ddof=1
    float sc   = 1.f / (sqrtf(var) + 1e-5f);
    red[0] = mean; red[1] = sc;
  }
  __syncthreads();
  const float mean = red[0], sc = red[1];

  if constexpr (LAST) {
#pragma unroll
    for (int r = 0; r < RT; r++)
#pragma unroll
      for (int ct = 0; ct < 4; ct++)
#pragma unroll
        for (int i = 0; i < 4; i++){
          int o = (wave + WAVES*r)*16 + kg*4 + i;
          int n = ct*16 + lrow;
          Outf[(size_t)b*(O*64) + o*64 + n] = lrelu((acc[r][ct][i] - mean)*sc);  // f32 output
        }
  } else {
#pragma unroll
    for (int r = 0; r < RT; r++)
#pragma unroll
      for (int ct = 0; ct < 4; ct++){
        int o0 = (wave + WAVES*r)*16 + kg*4;
        int n  = ct*16 + lrow;
        u16x4 pk;
#pragma unroll
        for (int i = 0; i < 4; i++) pk[i] = f2b(lrelu((acc[r][ct][i] - mean)*sc));
        *(u16x4*)(Xout + (size_t)b*64*O + (size_t)n*O + o0) = pk;  // (B,64,O) node-major
      }
  }
}

// ---------------------------------------------------------------------------
extern "C" void kernel_launch(void* const* d_in, const int* in_sizes, int n_in,
                              void* d_out, int out_size, void* d_ws, size_t ws_size,
                              hipStream_t stream)
{
  // ALL float inputs are float32 (proven by R3's dtype-flag experiment).
  const float* trees = (const float*)d_in[0];
  const int*   gidx  = (const int*)d_in[1];
  const float* w1 = (const float*)d_in[2];
  const float* g1 = (const float*)d_in[4];  const float* be1 = (const float*)d_in[5];
  const float* w2 = (const float*)d_in[6];
  const float* g2 = (const float*)d_in[8];  const float* be2 = (const float*)d_in[9];
  const float* w3 = (const float*)d_in[10];
  const float* g3 = (const float*)d_in[12]; const float* be3 = (const float*)d_in[13];
  const float* w4 = (const float*)d_in[14];
  const float* g4 = (const float*)d_in[16]; const float* be4 = (const float*)d_in[17];
  const float* cw1 = (const float*)d_in[18]; const float* cb1 = (const float*)d_in[19];
  const float* cw2 = (const float*)d_in[20]; const float* cb2 = (const float*)d_in[21];
  const float* cw3 = (const float*)d_in[22]; const float* cb3 = (const float*)d_in[23];
  // linear biases b1..b4 cancel under training-mode BN — unused.

  // ws: repacked conv weights + BN scratch + Xc3 (must NOT alias d_out).
  char* ws = (char*)d_ws;
  size_t off = 0;
  auto alloc = [&](size_t bytes)->char*{ char* p = ws + off; off += (bytes + 255) & ~(size_t)255; return p; };
  u16*   Wr1   = (u16*)  alloc(128*192*2);
  u16*   Wr2   = (u16*)  alloc(256*384*2);
  u16*   Wr3   = (u16*)  alloc(512*768*2);
  float* partA = (float*)alloc(64*4096*4);
  float* partB = (float*)alloc(64*4096*4);
  float* ss4   = (float*)alloc(2*4096*4);
  u16*   Xc3   = (u16*)  alloc((size_t)2048*64*256*2);   // 64 MB

  // d_out is (2048,512,64) FLOAT32 = 268 MB. Host MLP-phase scratch inside it;
  // everything here is dead before the final conv overwrites all of d_out.
  u16*   ob   = (u16*)d_out;                 // u16-unit view for offsets
  float* outF = (float*)d_out;
  float* Ya   = (float*)ob;                  // u16 [0, 16,777,216)  : f32 ping
  u16*   Wb1  = ob + 19660800;               // [.., 19,664,896)
  u16*   Wb2  = ob + 19664896;               // [.., 19,681,280)
  u16*   Wb3  = ob + 19681280;               // [.., 19,943,424)
  u16*   Wb4  = ob + 19943424;               // [.., 24,137,728)
  u16*   Xc2  = ob + 33554432;               // [.., 50,331,648)
  float* Yb   = (float*)(ob + 50331648);     // [.., 67,108,864)  : f32 pong  < 134,217,728 ✓

  // weight prep (2 launches)
  cvt_w_all <<<4372, 256, 0, stream>>>(w1, Wb1, w2, Wb2, w3, Wb3, w4, Wb4);
  repack_all<<<2016, 256, 0, stream>>>(cw1, Wr1, cw2, Wr2, cw3, Wr3);

  // MLP: gemm(+stats) -> next gemm finalizes+applies BN on its A-load.
  gemm_bn<64,64,4,1,1,4,false><<<dim3(32,1),  256, 0, stream>>>(trees, Wb1, nullptr, nullptr, nullptr, 0,  Ya, partA, 2048, 64,   64);
  gemm_bn<64,64,4,1,1,4,true ><<<dim3(32,4),  256, 0, stream>>>(Ya,    Wb2, partA,   g1,      be1,     32, Yb, partB, 2048, 256,  64);
  gemm_bn<64,64,4,1,1,4,true ><<<dim3(32,16), 256, 0, stream>>>(Yb,    Wb3, partB,   g2,      be2,     32, Ya, partA, 2048, 1024, 256);
  gemm_bn<128,256,2,4,4,4,true><<<dim3(16,16),512, 0, stream>>>(Ya,    Wb4, partA,   g3,      be3,     32, Yb, partB, 2048, 4096, 1024);
  bn_finalize<<<16, 256, 0, stream>>>(partB, g4, be4, ss4, 4096, 2048, 16);

  // tree-conv stack (best-measured config, R5/R7): 8 waves, RT=O/128,
  // 2 blocks/CU; conv1/conv2 2-stage pipeline, conv3 single-stage.
  conv_norm< 64,128,8,4,true ,false,true ><<<2048, 512, 0, stream>>>(nullptr, Yb, ss4, Wr1, cb1, gidx, Xc2, nullptr);
  conv_norm<128,256,8,4,true ,false,false><<<2048, 512, 0, stream>>>(Xc2, nullptr, nullptr, Wr2, cb2, gidx, Xc3, nullptr);
  conv_norm<256,512,8,4,false,true ,false><<<2048, 512, 0, stream>>>(Xc3, nullptr, nullptr, Wr3, cb3, gidx, nullptr, outF);
}